// Round 9
// baseline (144.015 us; speedup 1.0000x reference)
//
#include <hip/hip_runtime.h>
#include <hip/hip_bf16.h>
#include <hip/hip_fp16.h>

#define NH 8
#define ED 128
#define NB 8
#define NN 1024

typedef __attribute__((ext_vector_type(8))) short s16x8;
typedef __attribute__((ext_vector_type(8))) __bf16 bf16x8_t;
typedef __attribute__((ext_vector_type(4))) float f32x4;
typedef __attribute__((ext_vector_type(16))) float f32x16;
typedef __attribute__((ext_vector_type(4))) unsigned int u32x4;

#define LOG2E 1.4426950408889634f
#define SINIT -23.083120654223414f   /* -16 * log2(e) */

static __device__ __forceinline__ unsigned short f2bf(float f) {
    union { float f; unsigned u; } v; v.f = f;
    unsigned r = v.u + 0x7fffu + ((v.u >> 16) & 1u);
    return (unsigned short)(r >> 16);
}

static __device__ __forceinline__ f32x4 mfma16(s16x8 a, s16x8 b, f32x4 c) {
    return __builtin_amdgcn_mfma_f32_16x16x32_bf16(
        __builtin_bit_cast(bf16x8_t, a), __builtin_bit_cast(bf16x8_t, b), c, 0, 0, 0);
}

static __device__ __forceinline__ f32x16 mfma32(s16x8 a, s16x8 b, f32x16 c) {
    return __builtin_amdgcn_mfma_f32_32x32x16_bf16(
        __builtin_bit_cast(bf16x8_t, a), __builtin_bit_cast(bf16x8_t, b), c, 0, 0, 0);
}

static __device__ __forceinline__ unsigned cvtpk(float lo, float hi) {
    unsigned r;
    asm("v_cvt_pk_bf16_f32 %0, %1, %2" : "=v"(r) : "v"(lo), "v"(hi));
    return r;
}

// async global->LDS, 16B per lane; LDS dest is wave-uniform base (+ lane*16 by HW)
static __device__ __forceinline__ void gll16(const void* g, void* l) {
    __builtin_amdgcn_global_load_lds((const __attribute__((address_space(1))) void*)g,
                                     (__attribute__((address_space(3))) void*)l, 16, 0, 0);
}

// ---------- fused prep: cvt x -> bf16, transpose 4 weight mats -> bf16 ----------
__global__ __launch_bounds__(256) void prep_kernel(
    const float* __restrict__ x,
    const float* __restrict__ Wq, const float* __restrict__ Wk,
    const float* __restrict__ Wv, const float* __restrict__ Wo,
    unsigned short* __restrict__ xb,
    unsigned short* __restrict__ wqt, unsigned short* __restrict__ wkt,
    unsigned short* __restrict__ wvt, unsigned short* __restrict__ wot) {
    int bid = blockIdx.x, tid = threadIdx.x;
    if (bid < 1024) {
        int i = bid * 256 + tid;
        float4 v = ((const float4*)x)[i];
        unsigned long long pk = (unsigned long long)f2bf(v.x)
                              | ((unsigned long long)f2bf(v.y) << 16)
                              | ((unsigned long long)f2bf(v.z) << 32)
                              | ((unsigned long long)f2bf(v.w) << 48);
        ((unsigned long long*)xb)[i] = pk;
        return;
    }
    const float* in; unsigned short* outp; int rows_in, cols_in, i;
    if (bid < 1536)      { in = Wq; outp = wqt; rows_in = 128;  cols_in = 1024; i = (bid - 1024) * 256 + tid; }
    else if (bid < 2048) { in = Wk; outp = wkt; rows_in = 128;  cols_in = 1024; i = (bid - 1536) * 256 + tid; }
    else if (bid < 2560) { in = Wv; outp = wvt; rows_in = 128;  cols_in = 1024; i = (bid - 2048) * 256 + tid; }
    else                 { in = Wo; outp = wot; rows_in = 1024; cols_in = 128;  i = (bid - 2560) * 256 + tid; }
    int c = i / rows_in;
    int r = i - c * rows_in;
    outp[i] = f2bf(in[(size_t)r * cols_in + c]);
}

// ---------- prep dist v2: LDS-transpose, coalesced; stores d*log2e (f16), mask -> -65504 ----------
// grid 1024: bid = (b*8+qt)*16 + kt ; output layout identical to R8's dswz
__global__ __launch_bounds__(256) void prep_dist_kernel(
    const float* __restrict__ dist,
    const float* __restrict__ mask,
    unsigned short* __restrict__ dswz) {
    int bid = blockIdx.x;
    int kt = bid & 15;
    int t = bid >> 4;
    int qt = t & 7;
    int b = t >> 3;
    int tid = threadIdx.x;

    __shared__ float dtile[128][65];   // +1 pad: conflict-free scattered reads
    __shared__ float mrow[64];

    // coalesced load: 128 rows x 64 cols f32
    {
        int seg = tid & 15;            // 16 segs x 16B = 256B per row
        int r0 = tid >> 4;             // 16 rows per pass
        const float* src = dist + ((size_t)b * NN + qt * 128) * NN + kt * 64;
#pragma unroll
        for (int pass = 0; pass < 8; ++pass) {
            int row = pass * 16 + r0;
            f32x4 v = *(const f32x4*)(src + (size_t)row * NN + seg * 4);
            *(f32x4*)&dtile[row][seg * 4] = v;
        }
        if (tid < 64) mrow[tid] = mask[b * NN + kt * 64 + tid];
    }
    __syncthreads();

    int h = (tid >> 5) & 1;
    int row = (tid >> 6) * 32 + (tid & 31);
#pragma unroll
    for (int c = 0; c < 4; ++c) {
        unsigned short o[8];
#pragma unroll
        for (int u = 0; u < 8; ++u) {
            int col = (c >> 1) * 32 + (c & 1) * 16 + 4 * h + (u >> 2) * 8 + (u & 3);
            float dv = dtile[row][col] * LOG2E;
            o[u] = (mrow[col] == 0.0f) ? (unsigned short)0xFBFF
                                       : __half_as_ushort(__float2half_rn(dv));
        }
        u32x4 pk;
        pk[0] = (unsigned)o[0] | ((unsigned)o[1] << 16);
        pk[1] = (unsigned)o[2] | ((unsigned)o[3] << 16);
        pk[2] = (unsigned)o[4] | ((unsigned)o[5] << 16);
        pk[3] = (unsigned)o[6] | ((unsigned)o[7] << 16);
        *(u32x4*)(dswz + ((size_t)(bid * 4 + c) * 256 + tid) * 8) = pk;
    }
}

// ---------- QKV projection: q linear (scale includes log2e); K/V in gll slot layout ----------
__global__ __launch_bounds__(256) void qkv_kernel(
    const unsigned short* __restrict__ xb,
    const unsigned short* __restrict__ wqt,
    const unsigned short* __restrict__ wkt,
    const unsigned short* __restrict__ wvt,
    const float* __restrict__ bq, const float* __restrict__ bk, const float* __restrict__ bv,
    unsigned short* __restrict__ q_ws,
    unsigned short* __restrict__ k_ws,
    unsigned short* __restrict__ v_ws) {
    int bid = blockIdx.x;
    int mt = bid / 24, c = bid % 24;
    int which = c >> 3;
    int c0 = (c & 7) * 128;
    int m0 = mt * 128;
    int tid = threadIdx.x;
    int w = tid >> 6, lane = tid & 63, g = lane >> 4, r15 = lane & 15;
    int wr = (w >> 1) * 64, wc = (w & 1) * 64;

    const unsigned short* wt = (which == 0) ? wqt : (which == 1) ? wkt : wvt;
    const float* bias = (which == 0) ? bq : (which == 1) ? bk : bv;

    const f32x4 fzero = {0.f, 0.f, 0.f, 0.f};
    f32x4 acc[4][4];
#pragma unroll
    for (int i = 0; i < 4; i++)
#pragma unroll
        for (int j = 0; j < 4; j++) acc[i][j] = fzero;

#pragma unroll
    for (int kf = 0; kf < 4; kf++) {
        s16x8 af[4], bfr[4];
#pragma unroll
        for (int mf = 0; mf < 4; mf++)
            af[mf] = *(const s16x8*)(xb + (size_t)(m0 + wr + mf * 16 + r15) * ED + kf * 32 + g * 8);
#pragma unroll
        for (int nf = 0; nf < 4; nf++)
            bfr[nf] = *(const s16x8*)(wt + (size_t)(c0 + wc + nf * 16 + r15) * ED + kf * 32 + g * 8);
#pragma unroll
        for (int mf = 0; mf < 4; mf++)
#pragma unroll
            for (int nf = 0; nf < 4; nf++)
                acc[mf][nf] = mfma16(af[mf], bfr[nf], acc[mf][nf]);
    }

    // q scale = (1/sqrt(128)) * log2(e) so softmax can use native exp2
    float scale = (which == 0) ? 0.12751741566380696f : 1.0f;

#pragma unroll
    for (int nf = 0; nf < 4; nf++) {
        int col = c0 + wc + nf * 16 + r15;
        float bv_ = bias[col];
        int hh = col >> 7, e = col & 127;
#pragma unroll
        for (int mf = 0; mf < 4; mf++) {
#pragma unroll
            for (int rr = 0; rr < 4; rr++) {
                int row = m0 + wr + mf * 16 + g * 4 + rr;
                int bb = row >> 10, n = row & 1023;
                int bh = bb * NH + hh;
                float val = (acc[mf][nf][rr] + bv_) * scale;
                if (which == 0) {
                    q_ws[((size_t)bh * NN + n) * ED + e] = f2bf(val);
                } else if (which == 1) {
                    int ktl = n >> 6, k = n & 63;
                    int slot = (e >> 4) * 128 + ((e >> 3) & 1) * 64 + (k >> 5) * 32 + (k & 31);
                    k_ws[(size_t)(bh * 16 + ktl) * 8192 + slot * 8 + (e & 7)] = f2bf(val);
                } else {
                    int ktl = n >> 6, k = n & 63;
                    int slot = (k >> 4) * 256 + ((k >> 3) & 1) * 128 + (e >> 5) * 32 + (e & 31);
                    v_ws[(size_t)(bh * 16 + ktl) * 8192 + slot * 8 + (k & 7)] = f2bf(val);
                }
            }
        }
    }
}

// ---------- flash attention: R8 structure + dist reg-prefetch + exp2 softmax ----------
__global__ __launch_bounds__(256) void attn_kernel(
    const unsigned short* __restrict__ q_ws,
    const unsigned short* __restrict__ k_ws,
    const unsigned short* __restrict__ v_ws,
    const unsigned short* __restrict__ dswz,
    unsigned short* __restrict__ y_ws) {
    int p = blockIdx.x;
    int b = p & 7, r = p >> 3;
    int head = r >> 3, qt = r & 7;
    int bh = b * NH + head;
    int q0 = qt * 128;

    int tid = threadIdx.x;
    int w = tid >> 6, lane = tid & 63;
    int e31 = lane & 31, h = lane >> 5;
    bool h0 = (h == 0);

    __shared__ __align__(16) unsigned short Kl[2][8192];
    __shared__ __align__(16) unsigned short Vl[2][8192];

    const char* kg = (const char*)k_ws + (size_t)bh * 16 * 16384;
    const char* vg = (const char*)v_ws + (size_t)bh * 16 * 16384;
    const char* dq = (const char*)dswz + ((size_t)(b * 8 + qt) << 18);

    int qrow = q0 + w * 32 + e31;
    s16x8 qf[8];
    const unsigned short* qb = q_ws + ((size_t)bh * NN + qrow) * ED + h * 8;
#pragma unroll
    for (int es = 0; es < 8; ++es) qf[es] = *(const s16x8*)(qb + es * 16);

    const f32x16 fz16 = {0.f,0.f,0.f,0.f,0.f,0.f,0.f,0.f,0.f,0.f,0.f,0.f,0.f,0.f,0.f,0.f};
    f32x16 sini;
#pragma unroll
    for (int i = 0; i < 16; ++i) sini[i] = SINIT;   // -16*log2e folded into accumulator
    f32x16 o0 = fz16, o1 = fz16, o2 = fz16, o3 = fz16;
    float l_r = 0.f;

    u32x4 dchA[4], dchB[4];

    // prologue: stage tile 0 into buf 0; dist chunk 0 into dchA
#pragma unroll
    for (int pass = 0; pass < 4; ++pass) {
        gll16(kg + (pass * 256 + tid) * 16, (char*)&Kl[0][0] + pass * 4096 + w * 1024);
        gll16(vg + (pass * 256 + tid) * 16, (char*)&Vl[0][0] + pass * 4096 + w * 1024);
    }
#pragma unroll
    for (int c = 0; c < 4; ++c)
        dchA[c] = *(const u32x4*)(dq + ((size_t)c * 256 + tid) * 16);
    __syncthreads();

    auto iter = [&](int kt, int cur, u32x4* dU, u32x4* dL) __attribute__((always_inline)) {
        // issue next K/V tile + next dist chunk (full-iteration slack, drained at end barrier)
        if (kt < 15) {
            const char* kn = kg + (size_t)(kt + 1) * 16384;
            const char* vn = vg + (size_t)(kt + 1) * 16384;
            char* kd = (char*)&Kl[cur ^ 1][0] + w * 1024;
            char* vd = (char*)&Vl[cur ^ 1][0] + w * 1024;
#pragma unroll
            for (int pass = 0; pass < 4; ++pass) {
                gll16(kn + (pass * 256 + tid) * 16, kd + pass * 4096);
                gll16(vn + (pass * 256 + tid) * 16, vd + pass * 4096);
            }
#pragma unroll
            for (int c = 0; c < 4; ++c)
                dL[c] = *(const u32x4*)(dq + ((size_t)((kt + 1) * 4 + c) * 256 + tid) * 16);
        }

        // S^T = K Q^T (accumulator pre-initialized with -16*log2e)
        const char* Kp = (const char*)&Kl[cur][0] + h * 1024 + e31 * 16;
        f32x16 sA0 = sini, sA1 = sini;
#pragma unroll
        for (int es = 0; es < 8; ++es) {
            s16x8 kb0 = *(const s16x8*)(Kp + es * 2048);
            s16x8 kb1 = *(const s16x8*)(Kp + es * 2048 + 512);
            sA0 = mfma32(kb0, qf[es], sA0);
            sA1 = mfma32(kb1, qf[es], sA1);
        }

        // softmax: p = exp2(s + d')   (d' = dist*log2e, masked -> -65504 -> p = 0)
        float pp[32];
#pragma unroll
        for (int c = 0; c < 4; ++c) {
#pragma unroll
            for (int u = 0; u < 8; ++u) {
                int i = c * 8 + u;
                unsigned wv = dU[c][u >> 1];
                float dv = __half2float(__ushort_as_half(
                    (unsigned short)((u & 1) ? (wv >> 16) : (wv & 0xffff))));
                float sv = (i < 16) ? sA0[i] : sA1[i - 16];
                float pv = __builtin_exp2f(sv + dv);
                pp[i] = pv;
                l_r += pv;
            }
        }

        // pack P -> A-frags in-register, then PV
        const char* Vp = (const char*)&Vl[cur][0] + h * 2048 + e31 * 16;
#pragma unroll
        for (int kf = 0; kf < 2; ++kf) {
#pragma unroll
            for (int ks2 = 0; ks2 < 2; ++ks2) {
                const float* pb = &pp[kf * 16 + ks2 * 8];
                unsigned X0 = cvtpk(pb[0], pb[1]);
                unsigned X1 = cvtpk(pb[2], pb[3]);
                unsigned Y0 = cvtpk(pb[4], pb[5]);
                unsigned Y1 = cvtpk(pb[6], pb[7]);
                unsigned sx0 = (unsigned)__shfl_xor((int)X0, 32, 64);
                unsigned sx1 = (unsigned)__shfl_xor((int)X1, 32, 64);
                unsigned sy0 = (unsigned)__shfl_xor((int)Y0, 32, 64);
                unsigned sy1 = (unsigned)__shfl_xor((int)Y1, 32, 64);
                u32x4 pw;
                pw[0] = h0 ? X0 : sy0;
                pw[1] = h0 ? X1 : sy1;
                pw[2] = h0 ? sx0 : Y0;
                pw[3] = h0 ? sx1 : Y1;
                s16x8 pa = __builtin_bit_cast(s16x8, pw);
                int kstep = kf * 2 + ks2;
                const char* vp = Vp + kstep * 4096;
                o0 = mfma32(pa, *(const s16x8*)(vp), o0);
                o1 = mfma32(pa, *(const s16x8*)(vp + 512), o1);
                o2 = mfma32(pa, *(const s16x8*)(vp + 1024), o2);
                o3 = mfma32(pa, *(const s16x8*)(vp + 1536), o3);
            }
        }
        __syncthreads();   // drains this iter's glls/dist loads + guards cur-buffer reuse
    };

#pragma unroll 1
    for (int k2 = 0; k2 < 8; ++k2) {
        iter(2 * k2,     0, dchA, dchB);
        iter(2 * k2 + 1, 1, dchB, dchA);
    }

    // epilogue: merge l across h-halves, distribute inverse, write y
    float lt = l_r + __shfl_xor(l_r, 32, 64);
    float inv = (lt > 0.f) ? 1.0f / lt : 0.f;
#pragma unroll
    for (int rc = 0; rc < 4; ++rc) {
#pragma unroll
        for (int jj = 0; jj < 4; ++jj) {
            int qq = jj + 8 * rc + 4 * h;
            float iq = __shfl(inv, qq, 64);
            int row = q0 + w * 32 + qq;
            size_t base = ((size_t)b * NN + row) * (NH * ED) + head * ED + e31;
            y_ws[base]      = f2bf(o0[rc * 4 + jj] * iq);
            y_ws[base + 32] = f2bf(o1[rc * 4 + jj] * iq);
            y_ws[base + 64] = f2bf(o2[rc * 4 + jj] * iq);
            y_ws[base + 96] = f2bf(o3[rc * 4 + jj] * iq);
        }
    }
}

// ---------- output projection: [8192,1024] @ [1024,128] + bo, * mask ----------
__global__ __launch_bounds__(256) void oproj_kernel(
    const unsigned short* __restrict__ y_ws,
    const unsigned short* __restrict__ wot,
    const float* __restrict__ bo,
    const float* __restrict__ mask,
    float* __restrict__ outp) {
    int bid = blockIdx.x;
    int mt = bid >> 1, nt = bid & 1;
    int m0 = mt * 64, c0 = nt * 64;
    int tid = threadIdx.x;
    int w = tid >> 6, lane = tid & 63, g = lane >> 4, r15 = lane & 15;

    const f32x4 fzero = {0.f, 0.f, 0.f, 0.f};
    f32x4 acc[4];
#pragma unroll
    for (int i = 0; i < 4; i++) acc[i] = fzero;

    const unsigned short* arow = y_ws + (size_t)(m0 + w * 16 + r15) * (NH * ED);
    for (int kt = 0; kt < 32; ++kt) {
        s16x8 af = *(const s16x8*)(arow + kt * 32 + g * 8);
#pragma unroll
        for (int nf = 0; nf < 4; nf++) {
            s16x8 bfr = *(const s16x8*)(wot + (size_t)(c0 + nf * 16 + r15) * (NH * ED) + kt * 32 + g * 8);
            acc[nf] = mfma16(af, bfr, acc[nf]);
        }
    }
#pragma unroll
    for (int nf = 0; nf < 4; nf++) {
        int col = c0 + nf * 16 + r15;
        float bias = bo[col];
#pragma unroll
        for (int rr = 0; rr < 4; rr++) {
            int token = m0 + w * 16 + g * 4 + rr;
            outp[(size_t)token * ED + col] = (acc[nf][rr] + bias) * mask[token];
        }
    }
}

extern "C" void kernel_launch(void* const* d_in, const int* in_sizes, int n_in,
                              void* d_out, int out_size, void* d_ws, size_t ws_size,
                              hipStream_t stream) {
    const float* x    = (const float*)d_in[0];
    const float* dist = (const float*)d_in[1];
    const float* mask = (const float*)d_in[2];
    const float* Wq   = (const float*)d_in[3];
    const float* bq   = (const float*)d_in[4];
    const float* Wk   = (const float*)d_in[5];
    const float* bk   = (const float*)d_in[6];
    const float* Wv   = (const float*)d_in[7];
    const float* bv   = (const float*)d_in[8];
    const float* Wo   = (const float*)d_in[9];
    const float* bo   = (const float*)d_in[10];
    float* outp = (float*)d_out;

    char* ws = (char*)d_ws;
    unsigned short* xb   = (unsigned short*)(ws);                              // 2 MB
    unsigned short* wqt  = (unsigned short*)(ws + (2u << 20));                 // 256 KB
    unsigned short* wkt  = (unsigned short*)(ws + (2u << 20) + (256u << 10));
    unsigned short* wvt  = (unsigned short*)(ws + (2u << 20) + (512u << 10));
    unsigned short* wot  = (unsigned short*)(ws + (2u << 20) + (768u << 10));
    unsigned short* q_ws = (unsigned short*)(ws + (3u << 20));                 // 16 MB
    unsigned short* k_ws = (unsigned short*)(ws + (19u << 20));                // 16 MB (slot tiles)
    unsigned short* v_ws = (unsigned short*)(ws + (35u << 20));                // 16 MB (slot tiles)
    unsigned short* y_ws = (unsigned short*)(ws + (51u << 20));                // 16 MB
    unsigned short* dswz = (unsigned short*)(ws + (67u << 20));                // 16.78 MB f16 dist*log2e

    prep_kernel<<<3072, 256, 0, stream>>>(x, Wq, Wk, Wv, Wo, xb, wqt, wkt, wvt, wot);
    prep_dist_kernel<<<1024, 256, 0, stream>>>(dist, mask, dswz);
    qkv_kernel<<<1536, 256, 0, stream>>>(xb, wqt, wkt, wvt, bq, bk, bv, q_ws, k_ws, v_ws);
    attn_kernel<<<512, 256, 0, stream>>>(q_ws, k_ws, v_ws, dswz, y_ws);
    oproj_kernel<<<256, 256, 0, stream>>>(y_ws, wot, bo, mask, outp);
}

// Round 10
// 133.622 us; speedup vs baseline: 1.0778x; 1.0778x over previous
//
#include <hip/hip_runtime.h>
#include <hip/hip_bf16.h>
#include <hip/hip_fp16.h>

#define NH 8
#define ED 128
#define NB 8
#define NN 1024

typedef __attribute__((ext_vector_type(8))) short s16x8;
typedef __attribute__((ext_vector_type(8))) __bf16 bf16x8_t;
typedef __attribute__((ext_vector_type(4))) float f32x4;
typedef __attribute__((ext_vector_type(16))) float f32x16;
typedef __attribute__((ext_vector_type(4))) unsigned int u32x4;

#define LOG2E 1.4426950408889634f
#define SINIT -23.083120654223414f   /* -16 * log2(e) */

static __device__ __forceinline__ unsigned short f2bf(float f) {
    union { float f; unsigned u; } v; v.f = f;
    unsigned r = v.u + 0x7fffu + ((v.u >> 16) & 1u);
    return (unsigned short)(r >> 16);
}

static __device__ __forceinline__ f32x4 mfma16(s16x8 a, s16x8 b, f32x4 c) {
    return __builtin_amdgcn_mfma_f32_16x16x32_bf16(
        __builtin_bit_cast(bf16x8_t, a), __builtin_bit_cast(bf16x8_t, b), c, 0, 0, 0);
}

static __device__ __forceinline__ f32x16 mfma32(s16x8 a, s16x8 b, f32x16 c) {
    return __builtin_amdgcn_mfma_f32_32x32x16_bf16(
        __builtin_bit_cast(bf16x8_t, a), __builtin_bit_cast(bf16x8_t, b), c, 0, 0, 0);
}

static __device__ __forceinline__ unsigned cvtpk(float lo, float hi) {
    unsigned r;
    asm("v_cvt_pk_bf16_f32 %0, %1, %2" : "=v"(r) : "v"(lo), "v"(hi));
    return r;
}

// async global->LDS, 16B per lane; LDS dest is wave-uniform base (+ lane*16 by HW)
static __device__ __forceinline__ void gll16(const void* g, void* l) {
    __builtin_amdgcn_global_load_lds((const __attribute__((address_space(1))) void*)g,
                                     (__attribute__((address_space(3))) void*)l, 16, 0, 0);
}

// ---------- fused prep: cvt x -> bf16, transpose 4 weight mats -> bf16 ----------
__global__ __launch_bounds__(256) void prep_kernel(
    const float* __restrict__ x,
    const float* __restrict__ Wq, const float* __restrict__ Wk,
    const float* __restrict__ Wv, const float* __restrict__ Wo,
    unsigned short* __restrict__ xb,
    unsigned short* __restrict__ wqt, unsigned short* __restrict__ wkt,
    unsigned short* __restrict__ wvt, unsigned short* __restrict__ wot) {
    int bid = blockIdx.x, tid = threadIdx.x;
    if (bid < 1024) {
        int i = bid * 256 + tid;
        float4 v = ((const float4*)x)[i];
        unsigned long long pk = (unsigned long long)f2bf(v.x)
                              | ((unsigned long long)f2bf(v.y) << 16)
                              | ((unsigned long long)f2bf(v.z) << 32)
                              | ((unsigned long long)f2bf(v.w) << 48);
        ((unsigned long long*)xb)[i] = pk;
        return;
    }
    const float* in; unsigned short* outp; int rows_in, cols_in, i;
    if (bid < 1536)      { in = Wq; outp = wqt; rows_in = 128;  cols_in = 1024; i = (bid - 1024) * 256 + tid; }
    else if (bid < 2048) { in = Wk; outp = wkt; rows_in = 128;  cols_in = 1024; i = (bid - 1536) * 256 + tid; }
    else if (bid < 2560) { in = Wv; outp = wvt; rows_in = 128;  cols_in = 1024; i = (bid - 2048) * 256 + tid; }
    else                 { in = Wo; outp = wot; rows_in = 1024; cols_in = 128;  i = (bid - 2560) * 256 + tid; }
    int c = i / rows_in;
    int r = i - c * rows_in;
    outp[i] = f2bf(in[(size_t)r * cols_in + c]);
}

// ---------- prep dist v2: LDS-transpose, coalesced; stores d*log2e (f16), mask -> -65504 ----------
__global__ __launch_bounds__(256) void prep_dist_kernel(
    const float* __restrict__ dist,
    const float* __restrict__ mask,
    unsigned short* __restrict__ dswz) {
    int bid = blockIdx.x;
    int kt = bid & 15;
    int t = bid >> 4;
    int qt = t & 7;
    int b = t >> 3;
    int tid = threadIdx.x;

    __shared__ float dtile[128][65];
    __shared__ float mrow[64];

    {
        int seg = tid & 15;
        int r0 = tid >> 4;
        const float* src = dist + ((size_t)b * NN + qt * 128) * NN + kt * 64;
#pragma unroll
        for (int pass = 0; pass < 8; ++pass) {
            int row = pass * 16 + r0;
            f32x4 v = *(const f32x4*)(src + (size_t)row * NN + seg * 4);
            *(f32x4*)&dtile[row][seg * 4] = v;
        }
        if (tid < 64) mrow[tid] = mask[b * NN + kt * 64 + tid];
    }
    __syncthreads();

    int h = (tid >> 5) & 1;
    int row = (tid >> 6) * 32 + (tid & 31);
#pragma unroll
    for (int c = 0; c < 4; ++c) {
        unsigned short o[8];
#pragma unroll
        for (int u = 0; u < 8; ++u) {
            int col = (c >> 1) * 32 + (c & 1) * 16 + 4 * h + (u >> 2) * 8 + (u & 3);
            float dv = dtile[row][col] * LOG2E;
            o[u] = (mrow[col] == 0.0f) ? (unsigned short)0xFBFF
                                       : __half_as_ushort(__float2half_rn(dv));
        }
        u32x4 pk;
        pk[0] = (unsigned)o[0] | ((unsigned)o[1] << 16);
        pk[1] = (unsigned)o[2] | ((unsigned)o[3] << 16);
        pk[2] = (unsigned)o[4] | ((unsigned)o[5] << 16);
        pk[3] = (unsigned)o[6] | ((unsigned)o[7] << 16);
        *(u32x4*)(dswz + ((size_t)(bid * 4 + c) * 256 + tid) * 8) = pk;
    }
}

// ---------- QKV projection: q linear (scale includes log2e); K/V in gll slot layout ----------
__global__ __launch_bounds__(256) void qkv_kernel(
    const unsigned short* __restrict__ xb,
    const unsigned short* __restrict__ wqt,
    const unsigned short* __restrict__ wkt,
    const unsigned short* __restrict__ wvt,
    const float* __restrict__ bq, const float* __restrict__ bk, const float* __restrict__ bv,
    unsigned short* __restrict__ q_ws,
    unsigned short* __restrict__ k_ws,
    unsigned short* __restrict__ v_ws) {
    int bid = blockIdx.x;
    int mt = bid / 24, c = bid % 24;
    int which = c >> 3;
    int c0 = (c & 7) * 128;
    int m0 = mt * 128;
    int tid = threadIdx.x;
    int w = tid >> 6, lane = tid & 63, g = lane >> 4, r15 = lane & 15;
    int wr = (w >> 1) * 64, wc = (w & 1) * 64;

    const unsigned short* wt = (which == 0) ? wqt : (which == 1) ? wkt : wvt;
    const float* bias = (which == 0) ? bq : (which == 1) ? bk : bv;

    const f32x4 fzero = {0.f, 0.f, 0.f, 0.f};
    f32x4 acc[4][4];
#pragma unroll
    for (int i = 0; i < 4; i++)
#pragma unroll
        for (int j = 0; j < 4; j++) acc[i][j] = fzero;

#pragma unroll
    for (int kf = 0; kf < 4; kf++) {
        s16x8 af[4], bfr[4];
#pragma unroll
        for (int mf = 0; mf < 4; mf++)
            af[mf] = *(const s16x8*)(xb + (size_t)(m0 + wr + mf * 16 + r15) * ED + kf * 32 + g * 8);
#pragma unroll
        for (int nf = 0; nf < 4; nf++)
            bfr[nf] = *(const s16x8*)(wt + (size_t)(c0 + wc + nf * 16 + r15) * ED + kf * 32 + g * 8);
#pragma unroll
        for (int mf = 0; mf < 4; mf++)
#pragma unroll
            for (int nf = 0; nf < 4; nf++)
                acc[mf][nf] = mfma16(af[mf], bfr[nf], acc[mf][nf]);
    }

    // q scale = (1/sqrt(128)) * log2(e) so softmax can use native exp2
    float scale = (which == 0) ? 0.12751741566380696f : 1.0f;

#pragma unroll
    for (int nf = 0; nf < 4; nf++) {
        int col = c0 + wc + nf * 16 + r15;
        float bv_ = bias[col];
        int hh = col >> 7, e = col & 127;
#pragma unroll
        for (int mf = 0; mf < 4; mf++) {
#pragma unroll
            for (int rr = 0; rr < 4; rr++) {
                int row = m0 + wr + mf * 16 + g * 4 + rr;
                int bb = row >> 10, n = row & 1023;
                int bh = bb * NH + hh;
                float val = (acc[mf][nf][rr] + bv_) * scale;
                if (which == 0) {
                    q_ws[((size_t)bh * NN + n) * ED + e] = f2bf(val);
                } else if (which == 1) {
                    int ktl = n >> 6, k = n & 63;
                    int slot = (e >> 4) * 128 + ((e >> 3) & 1) * 64 + (k >> 5) * 32 + (k & 31);
                    k_ws[(size_t)(bh * 16 + ktl) * 8192 + slot * 8 + (e & 7)] = f2bf(val);
                } else {
                    int ktl = n >> 6, k = n & 63;
                    int slot = (k >> 4) * 256 + ((k >> 3) & 1) * 128 + (e >> 5) * 32 + (e & 31);
                    v_ws[(size_t)(bh * 16 + ktl) * 8192 + slot * 8 + (k & 7)] = f2bf(val);
                }
            }
        }
    }
}

// ---------- flash attention: R8 structure + exp2 softmax (dist loads within-iter) ----------
__global__ __launch_bounds__(256) void attn_kernel(
    const unsigned short* __restrict__ q_ws,
    const unsigned short* __restrict__ k_ws,
    const unsigned short* __restrict__ v_ws,
    const unsigned short* __restrict__ dswz,
    unsigned short* __restrict__ y_ws) {
    int p = blockIdx.x;
    int b = p & 7, r = p >> 3;
    int head = r >> 3, qt = r & 7;
    int bh = b * NH + head;
    int q0 = qt * 128;

    int tid = threadIdx.x;
    int w = tid >> 6, lane = tid & 63;
    int e31 = lane & 31, h = lane >> 5;
    bool h0 = (h == 0);

    __shared__ __align__(16) unsigned short Kl[2][8192];
    __shared__ __align__(16) unsigned short Vl[2][8192];

    const char* kg = (const char*)k_ws + (size_t)bh * 16 * 16384;
    const char* vg = (const char*)v_ws + (size_t)bh * 16 * 16384;
    const char* dq = (const char*)dswz + ((size_t)(b * 8 + qt) << 18);

    int qrow = q0 + w * 32 + e31;
    s16x8 qf[8];
    const unsigned short* qb = q_ws + ((size_t)bh * NN + qrow) * ED + h * 8;
#pragma unroll
    for (int es = 0; es < 8; ++es) qf[es] = *(const s16x8*)(qb + es * 16);

    const f32x16 fz16 = {0.f,0.f,0.f,0.f,0.f,0.f,0.f,0.f,0.f,0.f,0.f,0.f,0.f,0.f,0.f,0.f};
    f32x16 sini;
#pragma unroll
    for (int i = 0; i < 16; ++i) sini[i] = SINIT;   // -16*log2e folded into accumulator
    f32x16 o0 = fz16, o1 = fz16, o2 = fz16, o3 = fz16;
    float l_r = 0.f;

    // prologue: stage tile 0 into buf 0
#pragma unroll
    for (int pass = 0; pass < 4; ++pass) {
        gll16(kg + (pass * 256 + tid) * 16, (char*)&Kl[0][0] + pass * 4096 + w * 1024);
        gll16(vg + (pass * 256 + tid) * 16, (char*)&Vl[0][0] + pass * 4096 + w * 1024);
    }
    __syncthreads();

    for (int kt = 0; kt < 16; ++kt) {
        int cur = kt & 1;
        // issue next tile into nxt (full-iteration slack; drained by end-of-iter barrier)
        if (kt < 15) {
            const char* kn = kg + (size_t)(kt + 1) * 16384;
            const char* vn = vg + (size_t)(kt + 1) * 16384;
            char* kd = (char*)&Kl[cur ^ 1][0] + w * 1024;
            char* vd = (char*)&Vl[cur ^ 1][0] + w * 1024;
#pragma unroll
            for (int pass = 0; pass < 4; ++pass) {
                gll16(kn + (pass * 256 + tid) * 16, kd + pass * 4096);
                gll16(vn + (pass * 256 + tid) * 16, vd + pass * 4096);
            }
        }

        // coalesced f16 dist chunks (L2-resident; issued before QK^T, consumed after)
        u32x4 dch[4];
#pragma unroll
        for (int c = 0; c < 4; ++c)
            dch[c] = *(const u32x4*)(dq + ((size_t)(kt * 4 + c) * 256 + tid) * 16);

        // S^T = K Q^T (accumulator pre-initialized with -16*log2e)
        const char* Kp = (const char*)&Kl[cur][0] + h * 1024 + e31 * 16;
        f32x16 sA0 = sini, sA1 = sini;
#pragma unroll
        for (int es = 0; es < 8; ++es) {
            s16x8 kb0 = *(const s16x8*)(Kp + es * 2048);
            s16x8 kb1 = *(const s16x8*)(Kp + es * 2048 + 512);
            sA0 = mfma32(kb0, qf[es], sA0);
            sA1 = mfma32(kb1, qf[es], sA1);
        }

        // softmax: p = exp2(s + d')   (d' = dist*log2e, masked -> -65504 -> p = 0)
        float pp[32];
#pragma unroll
        for (int c = 0; c < 4; ++c) {
#pragma unroll
            for (int u = 0; u < 8; ++u) {
                int i = c * 8 + u;
                unsigned wv = dch[c][u >> 1];
                float dv = __half2float(__ushort_as_half(
                    (unsigned short)((u & 1) ? (wv >> 16) : (wv & 0xffff))));
                float sv = (i < 16) ? sA0[i] : sA1[i - 16];
                float pv = __builtin_exp2f(sv + dv);
                pp[i] = pv;
                l_r += pv;
            }
        }

        // pack P -> A-frags in-register (cvt_pk + shfl_xor(32)), then PV
        const char* Vp = (const char*)&Vl[cur][0] + h * 2048 + e31 * 16;
#pragma unroll
        for (int kf = 0; kf < 2; ++kf) {
#pragma unroll
            for (int ks2 = 0; ks2 < 2; ++ks2) {
                const float* pb = &pp[kf * 16 + ks2 * 8];
                unsigned X0 = cvtpk(pb[0], pb[1]);
                unsigned X1 = cvtpk(pb[2], pb[3]);
                unsigned Y0 = cvtpk(pb[4], pb[5]);
                unsigned Y1 = cvtpk(pb[6], pb[7]);
                unsigned sx0 = (unsigned)__shfl_xor((int)X0, 32, 64);
                unsigned sx1 = (unsigned)__shfl_xor((int)X1, 32, 64);
                unsigned sy0 = (unsigned)__shfl_xor((int)Y0, 32, 64);
                unsigned sy1 = (unsigned)__shfl_xor((int)Y1, 32, 64);
                u32x4 pw;
                pw[0] = h0 ? X0 : sy0;
                pw[1] = h0 ? X1 : sy1;
                pw[2] = h0 ? sx0 : Y0;
                pw[3] = h0 ? sx1 : Y1;
                s16x8 pa = __builtin_bit_cast(s16x8, pw);
                int kstep = kf * 2 + ks2;
                const char* vp = Vp + kstep * 4096;
                o0 = mfma32(pa, *(const s16x8*)(vp), o0);
                o1 = mfma32(pa, *(const s16x8*)(vp + 512), o1);
                o2 = mfma32(pa, *(const s16x8*)(vp + 1024), o2);
                o3 = mfma32(pa, *(const s16x8*)(vp + 1536), o3);
            }
        }
        __syncthreads();   // one barrier/iter: drains gll(nxt) + guards cur reuse
    }

    // epilogue: merge l across h-halves, distribute inverse, write y
    float lt = l_r + __shfl_xor(l_r, 32, 64);
    float inv = (lt > 0.f) ? 1.0f / lt : 0.f;
#pragma unroll
    for (int rc = 0; rc < 4; ++rc) {
#pragma unroll
        for (int jj = 0; jj < 4; ++jj) {
            int qq = jj + 8 * rc + 4 * h;
            float iq = __shfl(inv, qq, 64);
            int row = q0 + w * 32 + qq;
            size_t base = ((size_t)b * NN + row) * (NH * ED) + head * ED + e31;
            y_ws[base]      = f2bf(o0[rc * 4 + jj] * iq);
            y_ws[base + 32] = f2bf(o1[rc * 4 + jj] * iq);
            y_ws[base + 64] = f2bf(o2[rc * 4 + jj] * iq);
            y_ws[base + 96] = f2bf(o3[rc * 4 + jj] * iq);
        }
    }
}

// ---------- output projection: [8192,1024] @ [1024,128] + bo, * mask ----------
__global__ __launch_bounds__(256) void oproj_kernel(
    const unsigned short* __restrict__ y_ws,
    const unsigned short* __restrict__ wot,
    const float* __restrict__ bo,
    const float* __restrict__ mask,
    float* __restrict__ outp) {
    int bid = blockIdx.x;
    int mt = bid >> 1, nt = bid & 1;
    int m0 = mt * 64, c0 = nt * 64;
    int tid = threadIdx.x;
    int w = tid >> 6, lane = tid & 63, g = lane >> 4, r15 = lane & 15;

    const f32x4 fzero = {0.f, 0.f, 0.f, 0.f};
    f32x4 acc[4];
#pragma unroll
    for (int i = 0; i < 4; i++) acc[i] = fzero;

    const unsigned short* arow = y_ws + (size_t)(m0 + w * 16 + r15) * (NH * ED);
    for (int kt = 0; kt < 32; ++kt) {
        s16x8 af = *(const s16x8*)(arow + kt * 32 + g * 8);
#pragma unroll
        for (int nf = 0; nf < 4; nf++) {
            s16x8 bfr = *(const s16x8*)(wot + (size_t)(c0 + nf * 16 + r15) * (NH * ED) + kt * 32 + g * 8);
            acc[nf] = mfma16(af, bfr, acc[nf]);
        }
    }
#pragma unroll
    for (int nf = 0; nf < 4; nf++) {
        int col = c0 + nf * 16 + r15;
        float bias = bo[col];
#pragma unroll
        for (int rr = 0; rr < 4; rr++) {
            int token = m0 + w * 16 + g * 4 + rr;
            outp[(size_t)token * ED + col] = (acc[nf][rr] + bias) * mask[token];
        }
    }
}

extern "C" void kernel_launch(void* const* d_in, const int* in_sizes, int n_in,
                              void* d_out, int out_size, void* d_ws, size_t ws_size,
                              hipStream_t stream) {
    const float* x    = (const float*)d_in[0];
    const float* dist = (const float*)d_in[1];
    const float* mask = (const float*)d_in[2];
    const float* Wq   = (const float*)d_in[3];
    const float* bq   = (const float*)d_in[4];
    const float* Wk   = (const float*)d_in[5];
    const float* bk   = (const float*)d_in[6];
    const float* Wv   = (const float*)d_in[7];
    const float* bv   = (const float*)d_in[8];
    const float* Wo   = (const float*)d_in[9];
    const float* bo   = (const float*)d_in[10];
    float* outp = (float*)d_out;

    char* ws = (char*)d_ws;
    unsigned short* xb   = (unsigned short*)(ws);                              // 2 MB
    unsigned short* wqt  = (unsigned short*)(ws + (2u << 20));                 // 256 KB
    unsigned short* wkt  = (unsigned short*)(ws + (2u << 20) + (256u << 10));
    unsigned short* wvt  = (unsigned short*)(ws + (2u << 20) + (512u << 10));
    unsigned short* wot  = (unsigned short*)(ws + (2u << 20) + (768u << 10));
    unsigned short* q_ws = (unsigned short*)(ws + (3u << 20));                 // 16 MB
    unsigned short* k_ws = (unsigned short*)(ws + (19u << 20));                // 16 MB (slot tiles)
    unsigned short* v_ws = (unsigned short*)(ws + (35u << 20));                // 16 MB (slot tiles)
    unsigned short* y_ws = (unsigned short*)(ws + (51u << 20));                // 16 MB
    unsigned short* dswz = (unsigned short*)(ws + (67u << 20));                // 16.78 MB f16 dist*log2e

    prep_kernel<<<3072, 256, 0, stream>>>(x, Wq, Wk, Wv, Wo, xb, wqt, wkt, wvt, wot);
    prep_dist_kernel<<<1024, 256, 0, stream>>>(dist, mask, dswz);
    qkv_kernel<<<1536, 256, 0, stream>>>(xb, wqt, wkt, wvt, bq, bk, bv, q_ws, k_ws, v_ws);
    attn_kernel<<<512, 256, 0, stream>>>(q_ws, k_ws, v_ws, dswz, y_ws);
    oproj_kernel<<<256, 256, 0, stream>>>(y_ws, wot, bo, mask, outp);
}

// Round 11
// 129.404 us; speedup vs baseline: 1.1129x; 1.0326x over previous
//
#include <hip/hip_runtime.h>
#include <hip/hip_bf16.h>
#include <hip/hip_fp16.h>

#define NH 8
#define ED 128
#define NB 8
#define NN 1024

typedef __attribute__((ext_vector_type(8))) short s16x8;
typedef __attribute__((ext_vector_type(8))) __bf16 bf16x8_t;
typedef __attribute__((ext_vector_type(4))) float f32x4;
typedef __attribute__((ext_vector_type(16))) float f32x16;
typedef __attribute__((ext_vector_type(4))) unsigned int u32x4;

#define LOG2E 1.4426950408889634f
#define SINIT -23.083120654223414f   /* -16 * log2(e) */

static __device__ __forceinline__ unsigned short f2bf(float f) {
    union { float f; unsigned u; } v; v.f = f;
    unsigned r = v.u + 0x7fffu + ((v.u >> 16) & 1u);
    return (unsigned short)(r >> 16);
}

static __device__ __forceinline__ f32x4 mfma16(s16x8 a, s16x8 b, f32x4 c) {
    return __builtin_amdgcn_mfma_f32_16x16x32_bf16(
        __builtin_bit_cast(bf16x8_t, a), __builtin_bit_cast(bf16x8_t, b), c, 0, 0, 0);
}

static __device__ __forceinline__ f32x16 mfma32(s16x8 a, s16x8 b, f32x16 c) {
    return __builtin_amdgcn_mfma_f32_32x32x16_bf16(
        __builtin_bit_cast(bf16x8_t, a), __builtin_bit_cast(bf16x8_t, b), c, 0, 0, 0);
}

static __device__ __forceinline__ unsigned cvtpk(float lo, float hi) {
    unsigned r;
    asm("v_cvt_pk_bf16_f32 %0, %1, %2" : "=v"(r) : "v"(lo), "v"(hi));
    return r;
}

// async global->LDS, 16B per lane; LDS dest is wave-uniform base (+ lane*16 by HW)
static __device__ __forceinline__ void gll16(const void* g, void* l) {
    __builtin_amdgcn_global_load_lds((const __attribute__((address_space(1))) void*)g,
                                     (__attribute__((address_space(3))) void*)l, 16, 0, 0);
}

// ---------- fused prep: cvt x -> bf16, transpose 4 weight mats -> bf16 ----------
__global__ __launch_bounds__(256) void prep_kernel(
    const float* __restrict__ x,
    const float* __restrict__ Wq, const float* __restrict__ Wk,
    const float* __restrict__ Wv, const float* __restrict__ Wo,
    unsigned short* __restrict__ xb,
    unsigned short* __restrict__ wqt, unsigned short* __restrict__ wkt,
    unsigned short* __restrict__ wvt, unsigned short* __restrict__ wot) {
    int bid = blockIdx.x, tid = threadIdx.x;
    if (bid < 1024) {
        int i = bid * 256 + tid;
        float4 v = ((const float4*)x)[i];
        unsigned long long pk = (unsigned long long)f2bf(v.x)
                              | ((unsigned long long)f2bf(v.y) << 16)
                              | ((unsigned long long)f2bf(v.z) << 32)
                              | ((unsigned long long)f2bf(v.w) << 48);
        ((unsigned long long*)xb)[i] = pk;
        return;
    }
    const float* in; unsigned short* outp; int rows_in, cols_in, i;
    if (bid < 1536)      { in = Wq; outp = wqt; rows_in = 128;  cols_in = 1024; i = (bid - 1024) * 256 + tid; }
    else if (bid < 2048) { in = Wk; outp = wkt; rows_in = 128;  cols_in = 1024; i = (bid - 1536) * 256 + tid; }
    else if (bid < 2560) { in = Wv; outp = wvt; rows_in = 128;  cols_in = 1024; i = (bid - 2048) * 256 + tid; }
    else                 { in = Wo; outp = wot; rows_in = 1024; cols_in = 128;  i = (bid - 2560) * 256 + tid; }
    int c = i / rows_in;
    int r = i - c * rows_in;
    outp[i] = f2bf(in[(size_t)r * cols_in + c]);
}

// ---------- prep dist v2: LDS-transpose, coalesced; stores d*log2e (f16), mask -> -65504 ----------
__global__ __launch_bounds__(256) void prep_dist_kernel(
    const float* __restrict__ dist,
    const float* __restrict__ mask,
    unsigned short* __restrict__ dswz) {
    int bid = blockIdx.x;
    int kt = bid & 15;
    int t = bid >> 4;
    int qt = t & 7;
    int b = t >> 3;
    int tid = threadIdx.x;

    __shared__ float dtile[128][65];
    __shared__ float mrow[64];

    {
        int seg = tid & 15;
        int r0 = tid >> 4;
        const float* src = dist + ((size_t)b * NN + qt * 128) * NN + kt * 64;
#pragma unroll
        for (int pass = 0; pass < 8; ++pass) {
            int row = pass * 16 + r0;
            f32x4 v = *(const f32x4*)(src + (size_t)row * NN + seg * 4);
            *(f32x4*)&dtile[row][seg * 4] = v;
        }
        if (tid < 64) mrow[tid] = mask[b * NN + kt * 64 + tid];
    }
    __syncthreads();

    int h = (tid >> 5) & 1;
    int row = (tid >> 6) * 32 + (tid & 31);
#pragma unroll
    for (int c = 0; c < 4; ++c) {
        unsigned short o[8];
#pragma unroll
        for (int u = 0; u < 8; ++u) {
            int col = (c >> 1) * 32 + (c & 1) * 16 + 4 * h + (u >> 2) * 8 + (u & 3);
            float dv = dtile[row][col] * LOG2E;
            o[u] = (mrow[col] == 0.0f) ? (unsigned short)0xFBFF
                                       : __half_as_ushort(__float2half_rn(dv));
        }
        u32x4 pk;
        pk[0] = (unsigned)o[0] | ((unsigned)o[1] << 16);
        pk[1] = (unsigned)o[2] | ((unsigned)o[3] << 16);
        pk[2] = (unsigned)o[4] | ((unsigned)o[5] << 16);
        pk[3] = (unsigned)o[6] | ((unsigned)o[7] << 16);
        *(u32x4*)(dswz + ((size_t)(bid * 4 + c) * 256 + tid) * 8) = pk;
    }
}

// ---------- QKV projection: q linear (scale includes log2e); K/V in gll slot layout ----------
__global__ __launch_bounds__(256) void qkv_kernel(
    const unsigned short* __restrict__ xb,
    const unsigned short* __restrict__ wqt,
    const unsigned short* __restrict__ wkt,
    const unsigned short* __restrict__ wvt,
    const float* __restrict__ bq, const float* __restrict__ bk, const float* __restrict__ bv,
    unsigned short* __restrict__ q_ws,
    unsigned short* __restrict__ k_ws,
    unsigned short* __restrict__ v_ws) {
    int bid = blockIdx.x;
    int mt = bid / 24, c = bid % 24;
    int which = c >> 3;
    int c0 = (c & 7) * 128;
    int m0 = mt * 128;
    int tid = threadIdx.x;
    int w = tid >> 6, lane = tid & 63, g = lane >> 4, r15 = lane & 15;
    int wr = (w >> 1) * 64, wc = (w & 1) * 64;

    const unsigned short* wt = (which == 0) ? wqt : (which == 1) ? wkt : wvt;
    const float* bias = (which == 0) ? bq : (which == 1) ? bk : bv;

    const f32x4 fzero = {0.f, 0.f, 0.f, 0.f};
    f32x4 acc[4][4];
#pragma unroll
    for (int i = 0; i < 4; i++)
#pragma unroll
        for (int j = 0; j < 4; j++) acc[i][j] = fzero;

#pragma unroll
    for (int kf = 0; kf < 4; kf++) {
        s16x8 af[4], bfr[4];
#pragma unroll
        for (int mf = 0; mf < 4; mf++)
            af[mf] = *(const s16x8*)(xb + (size_t)(m0 + wr + mf * 16 + r15) * ED + kf * 32 + g * 8);
#pragma unroll
        for (int nf = 0; nf < 4; nf++)
            bfr[nf] = *(const s16x8*)(wt + (size_t)(c0 + wc + nf * 16 + r15) * ED + kf * 32 + g * 8);
#pragma unroll
        for (int mf = 0; mf < 4; mf++)
#pragma unroll
            for (int nf = 0; nf < 4; nf++)
                acc[mf][nf] = mfma16(af[mf], bfr[nf], acc[mf][nf]);
    }

    // q scale = (1/sqrt(128)) * log2(e) so softmax can use native exp2
    float scale = (which == 0) ? 0.12751741566380696f : 1.0f;

#pragma unroll
    for (int nf = 0; nf < 4; nf++) {
        int col = c0 + wc + nf * 16 + r15;
        float bv_ = bias[col];
        int hh = col >> 7, e = col & 127;
#pragma unroll
        for (int mf = 0; mf < 4; mf++) {
#pragma unroll
            for (int rr = 0; rr < 4; rr++) {
                int row = m0 + wr + mf * 16 + g * 4 + rr;
                int bb = row >> 10, n = row & 1023;
                int bh = bb * NH + hh;
                float val = (acc[mf][nf][rr] + bv_) * scale;
                if (which == 0) {
                    q_ws[((size_t)bh * NN + n) * ED + e] = f2bf(val);
                } else if (which == 1) {
                    int ktl = n >> 6, k = n & 63;
                    int slot = (e >> 4) * 128 + ((e >> 3) & 1) * 64 + (k >> 5) * 32 + (k & 31);
                    k_ws[(size_t)(bh * 16 + ktl) * 8192 + slot * 8 + (e & 7)] = f2bf(val);
                } else {
                    int ktl = n >> 6, k = n & 63;
                    int slot = (k >> 4) * 256 + ((k >> 3) & 1) * 128 + (e >> 5) * 32 + (e & 31);
                    v_ws[(size_t)(bh * 16 + ktl) * 8192 + slot * 8 + (k & 7)] = f2bf(val);
                }
            }
        }
    }
}

// ---------- flash attention: R10 structure + permlane pack + split l-chains ----------
__global__ __launch_bounds__(256) void attn_kernel(
    const unsigned short* __restrict__ q_ws,
    const unsigned short* __restrict__ k_ws,
    const unsigned short* __restrict__ v_ws,
    const unsigned short* __restrict__ dswz,
    unsigned short* __restrict__ y_ws) {
    int p = blockIdx.x;
    int b = p & 7, r = p >> 3;
    int head = r >> 3, qt = r & 7;
    int bh = b * NH + head;
    int q0 = qt * 128;

    int tid = threadIdx.x;
    int w = tid >> 6, lane = tid & 63;
    int e31 = lane & 31, h = lane >> 5;

    __shared__ __align__(16) unsigned short Kl[2][8192];
    __shared__ __align__(16) unsigned short Vl[2][8192];

    const char* kg = (const char*)k_ws + (size_t)bh * 16 * 16384;
    const char* vg = (const char*)v_ws + (size_t)bh * 16 * 16384;
    const char* dq = (const char*)dswz + ((size_t)(b * 8 + qt) << 18);

    int qrow = q0 + w * 32 + e31;
    s16x8 qf[8];
    const unsigned short* qb = q_ws + ((size_t)bh * NN + qrow) * ED + h * 8;
#pragma unroll
    for (int es = 0; es < 8; ++es) qf[es] = *(const s16x8*)(qb + es * 16);

    const f32x16 fz16 = {0.f,0.f,0.f,0.f,0.f,0.f,0.f,0.f,0.f,0.f,0.f,0.f,0.f,0.f,0.f,0.f};
    f32x16 sini;
#pragma unroll
    for (int i = 0; i < 16; ++i) sini[i] = SINIT;   // -16*log2e folded into accumulator
    f32x16 o0 = fz16, o1 = fz16, o2 = fz16, o3 = fz16;
    float lacc[4] = {0.f, 0.f, 0.f, 0.f};           // 4 independent accumulation chains

    // prologue: stage tile 0 into buf 0
#pragma unroll
    for (int pass = 0; pass < 4; ++pass) {
        gll16(kg + (pass * 256 + tid) * 16, (char*)&Kl[0][0] + pass * 4096 + w * 1024);
        gll16(vg + (pass * 256 + tid) * 16, (char*)&Vl[0][0] + pass * 4096 + w * 1024);
    }
    __syncthreads();

    for (int kt = 0; kt < 16; ++kt) {
        int cur = kt & 1;
        // issue next tile into nxt (full-iteration slack; drained by end-of-iter barrier)
        if (kt < 15) {
            const char* kn = kg + (size_t)(kt + 1) * 16384;
            const char* vn = vg + (size_t)(kt + 1) * 16384;
            char* kd = (char*)&Kl[cur ^ 1][0] + w * 1024;
            char* vd = (char*)&Vl[cur ^ 1][0] + w * 1024;
#pragma unroll
            for (int pass = 0; pass < 4; ++pass) {
                gll16(kn + (pass * 256 + tid) * 16, kd + pass * 4096);
                gll16(vn + (pass * 256 + tid) * 16, vd + pass * 4096);
            }
        }

        // coalesced f16 dist chunks (L2-resident; issued before QK^T, consumed after)
        u32x4 dch[4];
#pragma unroll
        for (int c = 0; c < 4; ++c)
            dch[c] = *(const u32x4*)(dq + ((size_t)(kt * 4 + c) * 256 + tid) * 16);

        // S^T = K Q^T (accumulator pre-initialized with -16*log2e)
        const char* Kp = (const char*)&Kl[cur][0] + h * 1024 + e31 * 16;
        f32x16 sA0 = sini, sA1 = sini;
#pragma unroll
        for (int es = 0; es < 8; ++es) {
            s16x8 kb0 = *(const s16x8*)(Kp + es * 2048);
            s16x8 kb1 = *(const s16x8*)(Kp + es * 2048 + 512);
            sA0 = mfma32(kb0, qf[es], sA0);
            sA1 = mfma32(kb1, qf[es], sA1);
        }

        // softmax: p = exp2(s + d'); 4 independent l-chains (breaks 32-deep serial fadd)
        float pp[32];
#pragma unroll
        for (int c = 0; c < 4; ++c) {
            float lc = 0.f;
#pragma unroll
            for (int u = 0; u < 8; ++u) {
                int i = c * 8 + u;
                unsigned wv = dch[c][u >> 1];
                float dv = __half2float(__ushort_as_half(
                    (unsigned short)((u & 1) ? (wv >> 16) : (wv & 0xffff))));
                float sv = (i < 16) ? sA0[i] : sA1[i - 16];
                float pv = __builtin_exp2f(sv + dv);
                pp[i] = pv;
                lc += pv;
            }
            lacc[c] += lc;
        }

        // pack P -> A-frags: cvt_pk + permlane32_swap (replaces shfl_xor + selects)
        const char* Vp = (const char*)&Vl[cur][0] + h * 2048 + e31 * 16;
#pragma unroll
        for (int kf = 0; kf < 2; ++kf) {
#pragma unroll
            for (int ks2 = 0; ks2 < 2; ++ks2) {
                const float* pb = &pp[kf * 16 + ks2 * 8];
                unsigned A0 = cvtpk(pb[0], pb[1]);
                unsigned A1 = cvtpk(pb[2], pb[3]);
                unsigned B0 = cvtpk(pb[4], pb[5]);
                unsigned B1 = cvtpk(pb[6], pb[7]);
                // after swap: A' = (lane<32 ? A : B[lane^32]), B' = (lane<32 ? A[lane^32] : B)
                asm("v_permlane32_swap_b32 %0, %1" : "+v"(A0), "+v"(B0));
                asm("v_permlane32_swap_b32 %0, %1" : "+v"(A1), "+v"(B1));
                u32x4 pw;
                pw[0] = A0;
                pw[1] = A1;
                pw[2] = B0;
                pw[3] = B1;
                s16x8 pa = __builtin_bit_cast(s16x8, pw);
                int kstep = kf * 2 + ks2;
                const char* vp = Vp + kstep * 4096;
                o0 = mfma32(pa, *(const s16x8*)(vp), o0);
                o1 = mfma32(pa, *(const s16x8*)(vp + 512), o1);
                o2 = mfma32(pa, *(const s16x8*)(vp + 1024), o2);
                o3 = mfma32(pa, *(const s16x8*)(vp + 1536), o3);
            }
        }
        __syncthreads();   // one barrier/iter: drains gll(nxt) + guards cur reuse
    }

    // epilogue: merge 4 chains + h-halves, distribute inverse, write y
    float l_r = (lacc[0] + lacc[1]) + (lacc[2] + lacc[3]);
    float lt = l_r + __shfl_xor(l_r, 32, 64);
    float inv = (lt > 0.f) ? 1.0f / lt : 0.f;
#pragma unroll
    for (int rc = 0; rc < 4; ++rc) {
#pragma unroll
        for (int jj = 0; jj < 4; ++jj) {
            int qq = jj + 8 * rc + 4 * h;
            float iq = __shfl(inv, qq, 64);
            int row = q0 + w * 32 + qq;
            size_t base = ((size_t)b * NN + row) * (NH * ED) + head * ED + e31;
            y_ws[base]      = f2bf(o0[rc * 4 + jj] * iq);
            y_ws[base + 32] = f2bf(o1[rc * 4 + jj] * iq);
            y_ws[base + 64] = f2bf(o2[rc * 4 + jj] * iq);
            y_ws[base + 96] = f2bf(o3[rc * 4 + jj] * iq);
        }
    }
}

// ---------- output projection: [8192,1024] @ [1024,128] + bo, * mask ----------
__global__ __launch_bounds__(256) void oproj_kernel(
    const unsigned short* __restrict__ y_ws,
    const unsigned short* __restrict__ wot,
    const float* __restrict__ bo,
    const float* __restrict__ mask,
    float* __restrict__ outp) {
    int bid = blockIdx.x;
    int mt = bid >> 1, nt = bid & 1;
    int m0 = mt * 64, c0 = nt * 64;
    int tid = threadIdx.x;
    int w = tid >> 6, lane = tid & 63, g = lane >> 4, r15 = lane & 15;

    const f32x4 fzero = {0.f, 0.f, 0.f, 0.f};
    f32x4 acc[4];
#pragma unroll
    for (int i = 0; i < 4; i++) acc[i] = fzero;

    const unsigned short* arow = y_ws + (size_t)(m0 + w * 16 + r15) * (NH * ED);
    for (int kt = 0; kt < 32; ++kt) {
        s16x8 af = *(const s16x8*)(arow + kt * 32 + g * 8);
#pragma unroll
        for (int nf = 0; nf < 4; nf++) {
            s16x8 bfr = *(const s16x8*)(wot + (size_t)(c0 + nf * 16 + r15) * (NH * ED) + kt * 32 + g * 8);
            acc[nf] = mfma16(af, bfr, acc[nf]);
        }
    }
#pragma unroll
    for (int nf = 0; nf < 4; nf++) {
        int col = c0 + nf * 16 + r15;
        float bias = bo[col];
#pragma unroll
        for (int rr = 0; rr < 4; rr++) {
            int token = m0 + w * 16 + g * 4 + rr;
            outp[(size_t)token * ED + col] = (acc[nf][rr] + bias) * mask[token];
        }
    }
}

extern "C" void kernel_launch(void* const* d_in, const int* in_sizes, int n_in,
                              void* d_out, int out_size, void* d_ws, size_t ws_size,
                              hipStream_t stream) {
    const float* x    = (const float*)d_in[0];
    const float* dist = (const float*)d_in[1];
    const float* mask = (const float*)d_in[2];
    const float* Wq   = (const float*)d_in[3];
    const float* bq   = (const float*)d_in[4];
    const float* Wk   = (const float*)d_in[5];
    const float* bk   = (const float*)d_in[6];
    const float* Wv   = (const float*)d_in[7];
    const float* bv   = (const float*)d_in[8];
    const float* Wo   = (const float*)d_in[9];
    const float* bo   = (const float*)d_in[10];
    float* outp = (float*)d_out;

    char* ws = (char*)d_ws;
    unsigned short* xb   = (unsigned short*)(ws);                              // 2 MB
    unsigned short* wqt  = (unsigned short*)(ws + (2u << 20));                 // 256 KB
    unsigned short* wkt  = (unsigned short*)(ws + (2u << 20) + (256u << 10));
    unsigned short* wvt  = (unsigned short*)(ws + (2u << 20) + (512u << 10));
    unsigned short* wot  = (unsigned short*)(ws + (2u << 20) + (768u << 10));
    unsigned short* q_ws = (unsigned short*)(ws + (3u << 20));                 // 16 MB
    unsigned short* k_ws = (unsigned short*)(ws + (19u << 20));                // 16 MB (slot tiles)
    unsigned short* v_ws = (unsigned short*)(ws + (35u << 20));                // 16 MB (slot tiles)
    unsigned short* y_ws = (unsigned short*)(ws + (51u << 20));                // 16 MB
    unsigned short* dswz = (unsigned short*)(ws + (67u << 20));                // 16.78 MB f16 dist*log2e

    prep_kernel<<<3072, 256, 0, stream>>>(x, Wq, Wk, Wv, Wo, xb, wqt, wkt, wvt, wot);
    prep_dist_kernel<<<1024, 256, 0, stream>>>(dist, mask, dswz);
    qkv_kernel<<<1536, 256, 0, stream>>>(xb, wqt, wkt, wvt, bq, bk, bv, q_ws, k_ws, v_ws);
    attn_kernel<<<512, 256, 0, stream>>>(q_ws, k_ws, v_ws, dswz, y_ws);
    oproj_kernel<<<256, 256, 0, stream>>>(y_ws, wot, bo, mask, outp);
}

// Round 12
// 126.379 us; speedup vs baseline: 1.1395x; 1.0239x over previous
//
#include <hip/hip_runtime.h>
#include <hip/hip_bf16.h>
#include <hip/hip_fp16.h>

#define NH 8
#define ED 128
#define NB 8
#define NN 1024

typedef __attribute__((ext_vector_type(8))) short s16x8;
typedef __attribute__((ext_vector_type(8))) __bf16 bf16x8_t;
typedef __attribute__((ext_vector_type(4))) float f32x4;
typedef __attribute__((ext_vector_type(16))) float f32x16;
typedef __attribute__((ext_vector_type(4))) unsigned int u32x4;

#define LOG2E 1.4426950408889634f
#define SINIT -23.083120654223414f   /* -16 * log2(e) */

static __device__ __forceinline__ unsigned short f2bf(float f) {
    union { float f; unsigned u; } v; v.f = f;
    unsigned r = v.u + 0x7fffu + ((v.u >> 16) & 1u);
    return (unsigned short)(r >> 16);
}

static __device__ __forceinline__ f32x4 mfma16(s16x8 a, s16x8 b, f32x4 c) {
    return __builtin_amdgcn_mfma_f32_16x16x32_bf16(
        __builtin_bit_cast(bf16x8_t, a), __builtin_bit_cast(bf16x8_t, b), c, 0, 0, 0);
}

static __device__ __forceinline__ f32x16 mfma32(s16x8 a, s16x8 b, f32x16 c) {
    return __builtin_amdgcn_mfma_f32_32x32x16_bf16(
        __builtin_bit_cast(bf16x8_t, a), __builtin_bit_cast(bf16x8_t, b), c, 0, 0, 0);
}

static __device__ __forceinline__ unsigned cvtpk(float lo, float hi) {
    unsigned r;
    asm("v_cvt_pk_bf16_f32 %0, %1, %2" : "=v"(r) : "v"(lo), "v"(hi));
    return r;
}

// async global->LDS, 16B per lane; LDS dest is wave-uniform base (+ lane*16 by HW)
static __device__ __forceinline__ void gll16(const void* g, void* l) {
    __builtin_amdgcn_global_load_lds((const __attribute__((address_space(1))) void*)g,
                                     (__attribute__((address_space(3))) void*)l, 16, 0, 0);
}

// ---------- merged prep: dist transform (bid<1024) | x cvt | 4 weight transposes ----------
__global__ __launch_bounds__(256) void prep_kernel(
    const float* __restrict__ x,
    const float* __restrict__ Wq, const float* __restrict__ Wk,
    const float* __restrict__ Wv, const float* __restrict__ Wo,
    const float* __restrict__ dist,
    const float* __restrict__ mask,
    unsigned short* __restrict__ xb,
    unsigned short* __restrict__ wqt, unsigned short* __restrict__ wkt,
    unsigned short* __restrict__ wvt, unsigned short* __restrict__ wot,
    unsigned short* __restrict__ dswz) {
    int bid = blockIdx.x, tid = threadIdx.x;

    if (bid < 1024) {
        // dist: f32 + mask -> f16 (d*log2e) swizzled chunks; masked keys -> -65504
        int kt = bid & 15;
        int t = bid >> 4;
        int qt = t & 7;
        int b = t >> 3;

        __shared__ float dtile[128][65];   // +1 pad: conflict-free scattered reads
        __shared__ float mrow[64];

        {
            int seg = tid & 15;
            int r0 = tid >> 4;
            const float* src = dist + ((size_t)b * NN + qt * 128) * NN + kt * 64;
#pragma unroll
            for (int pass = 0; pass < 8; ++pass) {
                int row = pass * 16 + r0;
                f32x4 v = *(const f32x4*)(src + (size_t)row * NN + seg * 4);
                *(f32x4*)&dtile[row][seg * 4] = v;
            }
            if (tid < 64) mrow[tid] = mask[b * NN + kt * 64 + tid];
        }
        __syncthreads();

        int h = (tid >> 5) & 1;
        int row = (tid >> 6) * 32 + (tid & 31);
#pragma unroll
        for (int c = 0; c < 4; ++c) {
            unsigned short o[8];
#pragma unroll
            for (int u = 0; u < 8; ++u) {
                int col = (c >> 1) * 32 + (c & 1) * 16 + 4 * h + (u >> 2) * 8 + (u & 3);
                float dv = dtile[row][col] * LOG2E;
                o[u] = (mrow[col] == 0.0f) ? (unsigned short)0xFBFF
                                           : __half_as_ushort(__float2half_rn(dv));
            }
            u32x4 pk;
            pk[0] = (unsigned)o[0] | ((unsigned)o[1] << 16);
            pk[1] = (unsigned)o[2] | ((unsigned)o[3] << 16);
            pk[2] = (unsigned)o[4] | ((unsigned)o[5] << 16);
            pk[3] = (unsigned)o[6] | ((unsigned)o[7] << 16);
            *(u32x4*)(dswz + ((size_t)(bid * 4 + c) * 256 + tid) * 8) = pk;
        }
        return;
    }

    if (bid < 2048) {
        int i = (bid - 1024) * 256 + tid;   // x: 4 f32 -> 4 bf16 per thread
        float4 v = ((const float4*)x)[i];
        unsigned long long pk = (unsigned long long)f2bf(v.x)
                              | ((unsigned long long)f2bf(v.y) << 16)
                              | ((unsigned long long)f2bf(v.z) << 32)
                              | ((unsigned long long)f2bf(v.w) << 48);
        ((unsigned long long*)xb)[i] = pk;
        return;
    }

    const float* in; unsigned short* outp; int rows_in, cols_in, i;
    if (bid < 2560)      { in = Wq; outp = wqt; rows_in = 128;  cols_in = 1024; i = (bid - 2048) * 256 + tid; }
    else if (bid < 3072) { in = Wk; outp = wkt; rows_in = 128;  cols_in = 1024; i = (bid - 2560) * 256 + tid; }
    else if (bid < 3584) { in = Wv; outp = wvt; rows_in = 128;  cols_in = 1024; i = (bid - 3072) * 256 + tid; }
    else                 { in = Wo; outp = wot; rows_in = 1024; cols_in = 128;  i = (bid - 3584) * 256 + tid; }
    int c = i / rows_in;
    int r = i - c * rows_in;
    outp[i] = f2bf(in[(size_t)r * cols_in + c]);
}

// ---------- QKV projection: q linear (scale includes log2e); K/V in gll slot layout ----------
__global__ __launch_bounds__(256) void qkv_kernel(
    const unsigned short* __restrict__ xb,
    const unsigned short* __restrict__ wqt,
    const unsigned short* __restrict__ wkt,
    const unsigned short* __restrict__ wvt,
    const float* __restrict__ bq, const float* __restrict__ bk, const float* __restrict__ bv,
    unsigned short* __restrict__ q_ws,
    unsigned short* __restrict__ k_ws,
    unsigned short* __restrict__ v_ws) {
    int bid = blockIdx.x;
    int mt = bid / 24, c = bid % 24;
    int which = c >> 3;
    int c0 = (c & 7) * 128;
    int m0 = mt * 128;
    int tid = threadIdx.x;
    int w = tid >> 6, lane = tid & 63, g = lane >> 4, r15 = lane & 15;
    int wr = (w >> 1) * 64, wc = (w & 1) * 64;

    const unsigned short* wt = (which == 0) ? wqt : (which == 1) ? wkt : wvt;
    const float* bias = (which == 0) ? bq : (which == 1) ? bk : bv;

    const f32x4 fzero = {0.f, 0.f, 0.f, 0.f};
    f32x4 acc[4][4];
#pragma unroll
    for (int i = 0; i < 4; i++)
#pragma unroll
        for (int j = 0; j < 4; j++) acc[i][j] = fzero;

#pragma unroll
    for (int kf = 0; kf < 4; kf++) {
        s16x8 af[4], bfr[4];
#pragma unroll
        for (int mf = 0; mf < 4; mf++)
            af[mf] = *(const s16x8*)(xb + (size_t)(m0 + wr + mf * 16 + r15) * ED + kf * 32 + g * 8);
#pragma unroll
        for (int nf = 0; nf < 4; nf++)
            bfr[nf] = *(const s16x8*)(wt + (size_t)(c0 + wc + nf * 16 + r15) * ED + kf * 32 + g * 8);
#pragma unroll
        for (int mf = 0; mf < 4; mf++)
#pragma unroll
            for (int nf = 0; nf < 4; nf++)
                acc[mf][nf] = mfma16(af[mf], bfr[nf], acc[mf][nf]);
    }

    // q scale = (1/sqrt(128)) * log2(e) so softmax can use native exp2
    float scale = (which == 0) ? 0.12751741566380696f : 1.0f;

#pragma unroll
    for (int nf = 0; nf < 4; nf++) {
        int col = c0 + wc + nf * 16 + r15;
        float bv_ = bias[col];
        int hh = col >> 7, e = col & 127;
#pragma unroll
        for (int mf = 0; mf < 4; mf++) {
#pragma unroll
            for (int rr = 0; rr < 4; rr++) {
                int row = m0 + wr + mf * 16 + g * 4 + rr;
                int bb = row >> 10, n = row & 1023;
                int bh = bb * NH + hh;
                float val = (acc[mf][nf][rr] + bv_) * scale;
                if (which == 0) {
                    q_ws[((size_t)bh * NN + n) * ED + e] = f2bf(val);
                } else if (which == 1) {
                    int ktl = n >> 6, k = n & 63;
                    int slot = (e >> 4) * 128 + ((e >> 3) & 1) * 64 + (k >> 5) * 32 + (k & 31);
                    k_ws[(size_t)(bh * 16 + ktl) * 8192 + slot * 8 + (e & 7)] = f2bf(val);
                } else {
                    int ktl = n >> 6, k = n & 63;
                    int slot = (k >> 4) * 256 + ((k >> 3) & 1) * 128 + (e >> 5) * 32 + (e & 31);
                    v_ws[(size_t)(bh * 16 + ktl) * 8192 + slot * 8 + (k & 7)] = f2bf(val);
                }
            }
        }
    }
}

// ---------- flash attention: R11 structure + s_setprio around MFMA clusters ----------
__global__ __launch_bounds__(256) void attn_kernel(
    const unsigned short* __restrict__ q_ws,
    const unsigned short* __restrict__ k_ws,
    const unsigned short* __restrict__ v_ws,
    const unsigned short* __restrict__ dswz,
    unsigned short* __restrict__ y_ws) {
    int p = blockIdx.x;
    int b = p & 7, r = p >> 3;
    int head = r >> 3, qt = r & 7;
    int bh = b * NH + head;
    int q0 = qt * 128;

    int tid = threadIdx.x;
    int w = tid >> 6, lane = tid & 63;
    int e31 = lane & 31, h = lane >> 5;

    __shared__ __align__(16) unsigned short Kl[2][8192];
    __shared__ __align__(16) unsigned short Vl[2][8192];

    const char* kg = (const char*)k_ws + (size_t)bh * 16 * 16384;
    const char* vg = (const char*)v_ws + (size_t)bh * 16 * 16384;
    const char* dq = (const char*)dswz + ((size_t)(b * 8 + qt) << 18);

    int qrow = q0 + w * 32 + e31;
    s16x8 qf[8];
    const unsigned short* qb = q_ws + ((size_t)bh * NN + qrow) * ED + h * 8;
#pragma unroll
    for (int es = 0; es < 8; ++es) qf[es] = *(const s16x8*)(qb + es * 16);

    const f32x16 fz16 = {0.f,0.f,0.f,0.f,0.f,0.f,0.f,0.f,0.f,0.f,0.f,0.f,0.f,0.f,0.f,0.f};
    f32x16 sini;
#pragma unroll
    for (int i = 0; i < 16; ++i) sini[i] = SINIT;   // -16*log2e folded into accumulator
    f32x16 o0 = fz16, o1 = fz16, o2 = fz16, o3 = fz16;
    float lacc[4] = {0.f, 0.f, 0.f, 0.f};           // 4 independent accumulation chains

    // prologue: stage tile 0 into buf 0
#pragma unroll
    for (int pass = 0; pass < 4; ++pass) {
        gll16(kg + (pass * 256 + tid) * 16, (char*)&Kl[0][0] + pass * 4096 + w * 1024);
        gll16(vg + (pass * 256 + tid) * 16, (char*)&Vl[0][0] + pass * 4096 + w * 1024);
    }
    __syncthreads();

    for (int kt = 0; kt < 16; ++kt) {
        int cur = kt & 1;
        // issue next tile into nxt (full-iteration slack; drained by end-of-iter barrier)
        if (kt < 15) {
            const char* kn = kg + (size_t)(kt + 1) * 16384;
            const char* vn = vg + (size_t)(kt + 1) * 16384;
            char* kd = (char*)&Kl[cur ^ 1][0] + w * 1024;
            char* vd = (char*)&Vl[cur ^ 1][0] + w * 1024;
#pragma unroll
            for (int pass = 0; pass < 4; ++pass) {
                gll16(kn + (pass * 256 + tid) * 16, kd + pass * 4096);
                gll16(vn + (pass * 256 + tid) * 16, vd + pass * 4096);
            }
        }

        // coalesced f16 dist chunks (L2-resident; issued before QK^T, consumed after)
        u32x4 dch[4];
#pragma unroll
        for (int c = 0; c < 4; ++c)
            dch[c] = *(const u32x4*)(dq + ((size_t)(kt * 4 + c) * 256 + tid) * 16);

        // S^T = K Q^T (accumulator pre-initialized with -16*log2e)
        const char* Kp = (const char*)&Kl[cur][0] + h * 1024 + e31 * 16;
        f32x16 sA0 = sini, sA1 = sini;
        __builtin_amdgcn_s_setprio(1);
#pragma unroll
        for (int es = 0; es < 8; ++es) {
            s16x8 kb0 = *(const s16x8*)(Kp + es * 2048);
            s16x8 kb1 = *(const s16x8*)(Kp + es * 2048 + 512);
            sA0 = mfma32(kb0, qf[es], sA0);
            sA1 = mfma32(kb1, qf[es], sA1);
        }
        __builtin_amdgcn_s_setprio(0);

        // softmax: p = exp2(s + d'); 4 independent l-chains
        float pp[32];
#pragma unroll
        for (int c = 0; c < 4; ++c) {
            float lc = 0.f;
#pragma unroll
            for (int u = 0; u < 8; ++u) {
                int i = c * 8 + u;
                unsigned wv = dch[c][u >> 1];
                float dv = __half2float(__ushort_as_half(
                    (unsigned short)((u & 1) ? (wv >> 16) : (wv & 0xffff))));
                float sv = (i < 16) ? sA0[i] : sA1[i - 16];
                float pv = __builtin_exp2f(sv + dv);
                pp[i] = pv;
                lc += pv;
            }
            lacc[c] += lc;
        }

        // pack P -> A-frags: cvt_pk + permlane32_swap, then PV
        const char* Vp = (const char*)&Vl[cur][0] + h * 2048 + e31 * 16;
        __builtin_amdgcn_s_setprio(1);
#pragma unroll
        for (int kf = 0; kf < 2; ++kf) {
#pragma unroll
            for (int ks2 = 0; ks2 < 2; ++ks2) {
                const float* pb = &pp[kf * 16 + ks2 * 8];
                unsigned A0 = cvtpk(pb[0], pb[1]);
                unsigned A1 = cvtpk(pb[2], pb[3]);
                unsigned B0 = cvtpk(pb[4], pb[5]);
                unsigned B1 = cvtpk(pb[6], pb[7]);
                asm("v_permlane32_swap_b32 %0, %1" : "+v"(A0), "+v"(B0));
                asm("v_permlane32_swap_b32 %0, %1" : "+v"(A1), "+v"(B1));
                u32x4 pw;
                pw[0] = A0;
                pw[1] = A1;
                pw[2] = B0;
                pw[3] = B1;
                s16x8 pa = __builtin_bit_cast(s16x8, pw);
                int kstep = kf * 2 + ks2;
                const char* vp = Vp + kstep * 4096;
                o0 = mfma32(pa, *(const s16x8*)(vp), o0);
                o1 = mfma32(pa, *(const s16x8*)(vp + 512), o1);
                o2 = mfma32(pa, *(const s16x8*)(vp + 1024), o2);
                o3 = mfma32(pa, *(const s16x8*)(vp + 1536), o3);
            }
        }
        __builtin_amdgcn_s_setprio(0);
        __syncthreads();   // one barrier/iter: drains gll(nxt) + guards cur reuse
    }

    // epilogue: merge 4 chains + h-halves, distribute inverse, write y
    float l_r = (lacc[0] + lacc[1]) + (lacc[2] + lacc[3]);
    float lt = l_r + __shfl_xor(l_r, 32, 64);
    float inv = (lt > 0.f) ? 1.0f / lt : 0.f;
#pragma unroll
    for (int rc = 0; rc < 4; ++rc) {
#pragma unroll
        for (int jj = 0; jj < 4; ++jj) {
            int qq = jj + 8 * rc + 4 * h;
            float iq = __shfl(inv, qq, 64);
            int row = q0 + w * 32 + qq;
            size_t base = ((size_t)b * NN + row) * (NH * ED) + head * ED + e31;
            y_ws[base]      = f2bf(o0[rc * 4 + jj] * iq);
            y_ws[base + 32] = f2bf(o1[rc * 4 + jj] * iq);
            y_ws[base + 64] = f2bf(o2[rc * 4 + jj] * iq);
            y_ws[base + 96] = f2bf(o3[rc * 4 + jj] * iq);
        }
    }
}

// ---------- output projection: [8192,1024] @ [1024,128] + bo, * mask ----------
__global__ __launch_bounds__(256) void oproj_kernel(
    const unsigned short* __restrict__ y_ws,
    const unsigned short* __restrict__ wot,
    const float* __restrict__ bo,
    const float* __restrict__ mask,
    float* __restrict__ outp) {
    int bid = blockIdx.x;
    int mt = bid >> 1, nt = bid & 1;
    int m0 = mt * 64, c0 = nt * 64;
    int tid = threadIdx.x;
    int w = tid >> 6, lane = tid & 63, g = lane >> 4, r15 = lane & 15;

    const f32x4 fzero = {0.f, 0.f, 0.f, 0.f};
    f32x4 acc[4];
#pragma unroll
    for (int i = 0; i < 4; i++) acc[i] = fzero;

    const unsigned short* arow = y_ws + (size_t)(m0 + w * 16 + r15) * (NH * ED);
    for (int kt = 0; kt < 32; ++kt) {
        s16x8 af = *(const s16x8*)(arow + kt * 32 + g * 8);
#pragma unroll
        for (int nf = 0; nf < 4; nf++) {
            s16x8 bfr = *(const s16x8*)(wot + (size_t)(c0 + nf * 16 + r15) * (NH * ED) + kt * 32 + g * 8);
            acc[nf] = mfma16(af, bfr, acc[nf]);
        }
    }
#pragma unroll
    for (int nf = 0; nf < 4; nf++) {
        int col = c0 + nf * 16 + r15;
        float bias = bo[col];
#pragma unroll
        for (int rr = 0; rr < 4; rr++) {
            int token = m0 + w * 16 + g * 4 + rr;
            outp[(size_t)token * ED + col] = (acc[nf][rr] + bias) * mask[token];
        }
    }
}

extern "C" void kernel_launch(void* const* d_in, const int* in_sizes, int n_in,
                              void* d_out, int out_size, void* d_ws, size_t ws_size,
                              hipStream_t stream) {
    const float* x    = (const float*)d_in[0];
    const float* dist = (const float*)d_in[1];
    const float* mask = (const float*)d_in[2];
    const float* Wq   = (const float*)d_in[3];
    const float* bq   = (const float*)d_in[4];
    const float* Wk   = (const float*)d_in[5];
    const float* bk   = (const float*)d_in[6];
    const float* Wv   = (const float*)d_in[7];
    const float* bv   = (const float*)d_in[8];
    const float* Wo   = (const float*)d_in[9];
    const float* bo   = (const float*)d_in[10];
    float* outp = (float*)d_out;

    char* ws = (char*)d_ws;
    unsigned short* xb   = (unsigned short*)(ws);                              // 2 MB
    unsigned short* wqt  = (unsigned short*)(ws + (2u << 20));                 // 256 KB
    unsigned short* wkt  = (unsigned short*)(ws + (2u << 20) + (256u << 10));
    unsigned short* wvt  = (unsigned short*)(ws + (2u << 20) + (512u << 10));
    unsigned short* wot  = (unsigned short*)(ws + (2u << 20) + (768u << 10));
    unsigned short* q_ws = (unsigned short*)(ws + (3u << 20));                 // 16 MB
    unsigned short* k_ws = (unsigned short*)(ws + (19u << 20));                // 16 MB (slot tiles)
    unsigned short* v_ws = (unsigned short*)(ws + (35u << 20));                // 16 MB (slot tiles)
    unsigned short* y_ws = (unsigned short*)(ws + (51u << 20));                // 16 MB
    unsigned short* dswz = (unsigned short*)(ws + (67u << 20));                // 16.78 MB f16 dist*log2e

    prep_kernel<<<4096, 256, 0, stream>>>(x, Wq, Wk, Wv, Wo, dist, mask,
                                          xb, wqt, wkt, wvt, wot, dswz);
    qkv_kernel<<<1536, 256, 0, stream>>>(xb, wqt, wkt, wvt, bq, bk, bv, q_ws, k_ws, v_ws);
    attn_kernel<<<512, 256, 0, stream>>>(q_ws, k_ws, v_ws, dswz, y_ws);
    oproj_kernel<<<256, 256, 0, stream>>>(y_ws, wot, bo, mask, outp);
}